// Round 2
// baseline (3681.173 us; speedup 1.0000x reference)
//
#include <hip/hip_runtime.h>

#define SEQ 4096
#define BATCH 8
#define HEADS 8
#define DMODEL 512
#define DK 64
#define PHI 128
#define CHUNK 1024
#define CROWS (CHUNK * BATCH)          // 8192 rows per chunk

// ---------------- fp32 SGEMM: C[M,N] = A[M,K] @ B[K,N] (+bias) ----------------
// 128x128 tile, BK=16, 256 threads, 8x8 micro-tile.
// Thread cols split as {tx*4..+4} and {64+tx*4..+4} to keep LDS B-frag reads 2-way.
template <bool BIAS>
__global__ __launch_bounds__(256)
void sgemm_kernel(const float* __restrict__ A, const float* __restrict__ B,
                  const float* __restrict__ bias, float* __restrict__ C,
                  int M, int N, int K)
{
    __shared__ __align__(16) float As[16][132];   // transposed A tile: As[k][m]
    __shared__ __align__(16) float Bs[16][128];   // Bs[k][n]
    const int t  = threadIdx.x;
    const int tx = t & 15;
    const int ty = t >> 4;
    const int bm = blockIdx.x * 128;
    const int bn = blockIdx.y * 128;

    float acc[8][8];
#pragma unroll
    for (int i = 0; i < 8; ++i)
#pragma unroll
        for (int j = 0; j < 8; ++j) acc[i][j] = 0.f;

    for (int k0 = 0; k0 < K; k0 += 16) {
#pragma unroll
        for (int i = 0; i < 2; ++i) {           // A tile: 128 rows x 16 k
            int lin = t + i * 256;
            int m   = lin >> 2;
            int kq  = (lin & 3) << 2;
            const float4 av = *(const float4*)(A + (size_t)(bm + m) * K + k0 + kq);
            As[kq + 0][m] = av.x; As[kq + 1][m] = av.y;
            As[kq + 2][m] = av.z; As[kq + 3][m] = av.w;
        }
#pragma unroll
        for (int i = 0; i < 2; ++i) {           // B tile: 16 k x 128 n
            int lin = t + i * 256;
            int kk  = lin >> 5;
            int n4  = (lin & 31) << 2;
            *(float4*)(&Bs[kk][n4]) = *(const float4*)(B + (size_t)(k0 + kk) * N + bn + n4);
        }
        __syncthreads();
#pragma unroll
        for (int k = 0; k < 16; ++k) {
            float af[8], bf[8];
            *(float4*)&af[0] = *(const float4*)&As[k][ty * 8];
            *(float4*)&af[4] = *(const float4*)&As[k][ty * 8 + 4];
            *(float4*)&bf[0] = *(const float4*)&Bs[k][tx * 4];
            *(float4*)&bf[4] = *(const float4*)&Bs[k][64 + tx * 4];
#pragma unroll
            for (int i = 0; i < 8; ++i)
#pragma unroll
                for (int j = 0; j < 8; ++j) acc[i][j] = fmaf(af[i], bf[j], acc[i][j]);
        }
        __syncthreads();
    }

#pragma unroll
    for (int i = 0; i < 8; ++i) {
        const int row = bm + ty * 8 + i;
        float4 o0, o1;
        o0.x = acc[i][0]; o0.y = acc[i][1]; o0.z = acc[i][2]; o0.w = acc[i][3];
        o1.x = acc[i][4]; o1.y = acc[i][5]; o1.z = acc[i][6]; o1.w = acc[i][7];
        if (BIAS) {
            const float4 b0 = *(const float4*)(bias + bn + tx * 4);
            const float4 b1 = *(const float4*)(bias + bn + 64 + tx * 4);
            o0.x += b0.x; o0.y += b0.y; o0.z += b0.z; o0.w += b0.w;
            o1.x += b1.x; o1.y += b1.y; o1.z += b1.z; o1.w += b1.w;
        }
        *(float4*)(C + (size_t)row * N + bn + tx * 4)      = o0;
        *(float4*)(C + (size_t)row * N + bn + 64 + tx * 4) = o1;
    }
}

// ---------------- dpfp: [CROWS*8, 64] -> [CROWS*8, 128], L1-normalized ----------------
// One wave per row. xcat = [relu(x), relu(-x)]; y[i] = xcat[i]*xcat[(i-1)%128]; y /= sum(y)+eps
__global__ __launch_bounds__(256)
void dpfp_kernel(const float* __restrict__ X, float* __restrict__ Y)
{
    const int gid  = blockIdx.x * 256 + threadIdx.x;
    const int wid  = gid >> 6;                 // row id
    const int lane = threadIdx.x & 63;
    const float xv = X[(size_t)wid * 64 + lane];
    const float ap = fmaxf(xv, 0.f);
    const float an = fmaxf(-xv, 0.f);
    const float a_prev = __shfl(ap, (lane + 63) & 63);   // lane-1 (lane0 -> lane63)
    const float b_prev = __shfl(an, (lane + 63) & 63);
    // out[lane]    = xcat[lane]   * xcat[lane-1 mod 128]
    // out[64+lane] = xcat[64+lane]* xcat[63+lane]
    const float y0 = ap * ((lane == 0) ? b_prev : a_prev);
    const float y1 = an * ((lane == 0) ? a_prev : b_prev);
    float s = y0 + y1;
    s += __shfl_xor(s, 1);
    s += __shfl_xor(s, 2);
    s += __shfl_xor(s, 4);
    s += __shfl_xor(s, 8);
    s += __shfl_xor(s, 16);
    s += __shfl_xor(s, 32);
    const float inv = 1.f / (s + 1e-6f);
    Y[(size_t)wid * 128 + lane]      = y0 * inv;
    Y[(size_t)wid * 128 + 64 + lane] = y1 * inv;
}

// ---------------- gate: beta = sigmoid(x @ Wg), [32768, 8], whole sequence ----------------
__global__ __launch_bounds__(256)
void gemm_g_kernel(const float* __restrict__ X, const float* __restrict__ Wg,
                   float* __restrict__ Bt)
{
    const int idx = blockIdx.x * 256 + threadIdx.x;   // 262144 total
    const int row = idx >> 3;
    const int c   = idx & 7;
    const float4* x4 = (const float4*)(X + (size_t)row * DMODEL);
    float acc = 0.f;
    for (int k4 = 0; k4 < 128; ++k4) {
        const float4 xv = x4[k4];
        acc = fmaf(xv.x, Wg[(k4 * 4 + 0) * 8 + c], acc);
        acc = fmaf(xv.y, Wg[(k4 * 4 + 1) * 8 + c], acc);
        acc = fmaf(xv.z, Wg[(k4 * 4 + 2) * 8 + c], acc);
        acc = fmaf(xv.w, Wg[(k4 * 4 + 3) * 8 + c], acc);
    }
    Bt[idx] = 1.f / (1.f + expf(-acc));
}

// ---------------- scan ----------------
// 16-lane sum via DPP row_ror adds (VALU pipe, keeps DS pipe free for staging).
__device__ __forceinline__ float rowsum16(float x)
{
    x += __int_as_float(__builtin_amdgcn_update_dpp(0, __float_as_int(x), 0x121, 0xF, 0xF, true)); // row_ror:1
    x += __int_as_float(__builtin_amdgcn_update_dpp(0, __float_as_int(x), 0x122, 0xF, 0xF, true)); // row_ror:2
    x += __int_as_float(__builtin_amdgcn_update_dpp(0, __float_as_int(x), 0x124, 0xF, 0xF, true)); // row_ror:4
    x += __int_as_float(__builtin_amdgcn_update_dpp(0, __float_as_int(x), 0x128, 0xF, 0xF, true)); // row_ror:8
    return x;
}

// Row-independent delta-rule chains, one CHUNK of steps. Block = (b,h, row-group of 16).
// 256 threads = 16 rows x 16 lanes; each thread holds w[8] (its row's 8 cols).
// W state persists across chunk launches in Wst (2 MB in d_ws).
__global__ __launch_bounds__(256)
void scan_kernel(const float* __restrict__ Qp, const float* __restrict__ Kp,
                 const float* __restrict__ Vd, const float* __restrict__ Bt,
                 float* __restrict__ outs, float* __restrict__ Wst,
                 int s0, int first)
{
    const int blk = blockIdx.x;
    const int bh  = blk & 63;
    const int rg  = blk >> 6;
    const int b   = bh >> 3;
    const int h   = bh & 7;
    const int t   = threadIdx.x;
    const int lane16 = t & 15;
    const int rloc   = t >> 4;
    const int cb     = lane16 * 8;

    __shared__ __align__(16) float sk[2][PHI];
    __shared__ __align__(16) float sq[2][PHI];
    __shared__ __align__(16) float sv[2][16];
    __shared__ float sb[2];

    float w[8];
    float* wslot = Wst + (size_t)blk * 2048 + t * 8;
    if (first) {
#pragma unroll
        for (int j = 0; j < 8; ++j) w[j] = 0.f;
    } else {
        const float4 w0 = *(const float4*)(wslot);
        const float4 w1 = *(const float4*)(wslot + 4);
        w[0] = w0.x; w[1] = w0.y; w[2] = w0.z; w[3] = w0.w;
        w[4] = w1.x; w[5] = w1.y; w[6] = w1.z; w[7] = w1.w;
    }

    // staging roles: t<32: k float4 #t; t<64: q float4 #(t-32); t<68: v float4; t==68: beta
    auto load_pref = [&](int s, float4& pf, float& pb) {
        if (t < 32) {
            pf = *(const float4*)(Kp + ((size_t)(s * BATCH + b) * HEADS + h) * PHI + t * 4);
        } else if (t < 64) {
            pf = *(const float4*)(Qp + ((size_t)(s * BATCH + b) * HEADS + h) * PHI + (t - 32) * 4);
        } else if (t < 68) {
            pf = *(const float4*)(Vd + (size_t)(s * BATCH + b) * DMODEL + h * DK + rg * 16 + (t - 64) * 4);
        } else if (t == 68) {
            pb = Bt[(size_t)((s0 + s) * BATCH + b) * HEADS + h];
        }
    };
    auto store_pref = [&](int nb, const float4& pf, float pb) {
        if (t < 32) {
            *(float4*)(&sk[nb][t * 4]) = pf;
        } else if (t < 64) {
            *(float4*)(&sq[nb][(t - 32) * 4]) = pf;
        } else if (t < 68) {
            *(float4*)(&sv[nb][(t - 64) * 4]) = pf;
        } else if (t == 68) {
            sb[nb] = pb;
        }
    };

    {
        float4 pf = {0, 0, 0, 0}; float pb = 0.f;
        load_pref(0, pf, pb);
        store_pref(0, pf, pb);
    }

#pragma unroll 2
    for (int s = 0; s < CHUNK; ++s) {
        __syncthreads();                       // buf[s&1] ready for everyone
        const int buf = s & 1;

        // prefetch step s+1 into registers (latency hidden by compute below)
        float4 pf = {0, 0, 0, 0}; float pb = 0.f;
        const int sp = (s + 1 < CHUNK) ? (s + 1) : s;
        load_pref(sp, pf, pb);

        const float4 k0 = *(const float4*)&sk[buf][cb];
        const float4 k1 = *(const float4*)&sk[buf][cb + 4];
        float a = w[0] * k0.x + w[1] * k0.y + w[2] * k0.z + w[3] * k0.w
                + w[4] * k1.x + w[5] * k1.y + w[6] * k1.z + w[7] * k1.w;
        a = rowsum16(a);
        const float d = sb[buf] * (sv[buf][rloc] - a);

        const float4 q0 = *(const float4*)&sq[buf][cb];
        const float4 q1 = *(const float4*)&sq[buf][cb + 4];
        w[0] = fmaf(d, k0.x, w[0]);
        w[1] = fmaf(d, k0.y, w[1]);
        w[2] = fmaf(d, k0.z, w[2]);
        w[3] = fmaf(d, k0.w, w[3]);
        w[4] = fmaf(d, k1.x, w[4]);
        w[5] = fmaf(d, k1.y, w[5]);
        w[6] = fmaf(d, k1.z, w[6]);
        w[7] = fmaf(d, k1.w, w[7]);
        float o = w[0] * q0.x + w[1] * q0.y + w[2] * q0.z + w[3] * q0.w
                + w[4] * q1.x + w[5] * q1.y + w[6] * q1.z + w[7] * q1.w;
        o = rowsum16(o);
        if (lane16 == 0)
            outs[(size_t)(s * BATCH + b) * DMODEL + h * DK + rg * 16 + rloc] = o;

        store_pref(buf ^ 1, pf, pb);           // made visible by next barrier
    }

    // persist state for next chunk
    float4 w0, w1;
    w0.x = w[0]; w0.y = w[1]; w0.z = w[2]; w0.w = w[3];
    w1.x = w[4]; w1.y = w[5]; w1.z = w[6]; w1.w = w[7];
    *(float4*)(wslot)     = w0;
    *(float4*)(wslot + 4) = w1;
}

extern "C" void kernel_launch(void* const* d_in, const int* in_sizes, int n_in,
                              void* d_out, int out_size, void* d_ws, size_t ws_size,
                              hipStream_t stream)
{
    const float* x  = (const float*)d_in[0];
    const float* Wq = (const float*)d_in[1];
    const float* Wk = (const float*)d_in[2];
    const float* Wv = (const float*)d_in[3];
    const float* Wg = (const float*)d_in[4];
    const float* Wo = (const float*)d_in[5];
    const float* bo = (const float*)d_in[6];
    float* out = (float*)d_out;

    // workspace (floats), chunked to ~104 MB total:
    //   Qp[CROWS*1024] Kp[CROWS*1024] Vd[CROWS*512] tmp[CROWS*512] Bt[32768*8] Wst[256*2048]
    float* ws  = (float*)d_ws;
    float* Qp  = ws;
    float* Kp  = Qp + (size_t)CROWS * 1024;
    float* Vd  = Kp + (size_t)CROWS * 1024;
    float* tmp = Vd + (size_t)CROWS * 512;
    float* Bt  = tmp + (size_t)CROWS * 512;
    float* Wst = Bt + (size_t)(SEQ * BATCH) * 8;
    (void)in_sizes; (void)n_in; (void)out_size; (void)ws_size;

    const dim3 gg(CROWS / 128, 4);   // (64, 4) = 256 workgroups
    const int NCH = SEQ / CHUNK;     // 4

    gemm_g_kernel<<<(SEQ * BATCH * 8) / 256, 256, 0, stream>>>(x, Wg, Bt);

    for (int c = 0; c < NCH; ++c) {
        const float* xc = x + (size_t)c * CROWS * DMODEL;
        sgemm_kernel<false><<<gg, 256, 0, stream>>>(xc, Wq, nullptr, tmp, CROWS, DMODEL, DMODEL);
        dpfp_kernel<<<(CROWS * 8) / 4, 256, 0, stream>>>(tmp, Qp);
        sgemm_kernel<false><<<gg, 256, 0, stream>>>(xc, Wk, nullptr, tmp, CROWS, DMODEL, DMODEL);
        dpfp_kernel<<<(CROWS * 8) / 4, 256, 0, stream>>>(tmp, Kp);
        sgemm_kernel<false><<<gg, 256, 0, stream>>>(xc, Wv, nullptr, Vd, CROWS, DMODEL, DMODEL);
        scan_kernel<<<256, 256, 0, stream>>>(Qp, Kp, Vd, Bt, tmp, Wst,
                                             c * CHUNK, c == 0 ? 1 : 0);
        sgemm_kernel<true><<<gg, 256, 0, stream>>>(tmp, Wo, bo,
                                                   out + (size_t)c * CROWS * DMODEL,
                                                   CROWS, DMODEL, DMODEL);
    }
}

// Round 3
// 2104.222 us; speedup vs baseline: 1.7494x; 1.7494x over previous
//
#include <hip/hip_runtime.h>

#define SEQ 4096
#define BATCH 8
#define HEADS 8
#define DMODEL 512
#define DK 64
#define PHI 128
#define CHUNK 1024
#define CROWS (CHUNK * BATCH)          // 8192 rows per chunk
#define SB 32                          // scan superblock (steps staged per barrier)
#define NSB (CHUNK / SB)               // 32

// ---------------- fp32 SGEMM: C[M,N] = A[M,K] @ B[K,N] (+bias) ----------------
// 128x128 tile, BK=16, 256 threads, 8x8 micro-tile.
template <bool BIAS>
__global__ __launch_bounds__(256)
void sgemm_kernel(const float* __restrict__ A, const float* __restrict__ B,
                  const float* __restrict__ bias, float* __restrict__ C,
                  int M, int N, int K)
{
    __shared__ __align__(16) float As[16][132];   // transposed A tile: As[k][m]
    __shared__ __align__(16) float Bs[16][128];   // Bs[k][n]
    const int t  = threadIdx.x;
    const int tx = t & 15;
    const int ty = t >> 4;
    const int bm = blockIdx.x * 128;
    const int bn = blockIdx.y * 128;

    float acc[8][8];
#pragma unroll
    for (int i = 0; i < 8; ++i)
#pragma unroll
        for (int j = 0; j < 8; ++j) acc[i][j] = 0.f;

    for (int k0 = 0; k0 < K; k0 += 16) {
#pragma unroll
        for (int i = 0; i < 2; ++i) {           // A tile: 128 rows x 16 k
            int lin = t + i * 256;
            int m   = lin >> 2;
            int kq  = (lin & 3) << 2;
            const float4 av = *(const float4*)(A + (size_t)(bm + m) * K + k0 + kq);
            As[kq + 0][m] = av.x; As[kq + 1][m] = av.y;
            As[kq + 2][m] = av.z; As[kq + 3][m] = av.w;
        }
#pragma unroll
        for (int i = 0; i < 2; ++i) {           // B tile: 16 k x 128 n
            int lin = t + i * 256;
            int kk  = lin >> 5;
            int n4  = (lin & 31) << 2;
            *(float4*)(&Bs[kk][n4]) = *(const float4*)(B + (size_t)(k0 + kk) * N + bn + n4);
        }
        __syncthreads();
#pragma unroll
        for (int k = 0; k < 16; ++k) {
            float af[8], bf[8];
            *(float4*)&af[0] = *(const float4*)&As[k][ty * 8];
            *(float4*)&af[4] = *(const float4*)&As[k][ty * 8 + 4];
            *(float4*)&bf[0] = *(const float4*)&Bs[k][tx * 4];
            *(float4*)&bf[4] = *(const float4*)&Bs[k][64 + tx * 4];
#pragma unroll
            for (int i = 0; i < 8; ++i)
#pragma unroll
                for (int j = 0; j < 8; ++j) acc[i][j] = fmaf(af[i], bf[j], acc[i][j]);
        }
        __syncthreads();
    }

#pragma unroll
    for (int i = 0; i < 8; ++i) {
        const int row = bm + ty * 8 + i;
        float4 o0, o1;
        o0.x = acc[i][0]; o0.y = acc[i][1]; o0.z = acc[i][2]; o0.w = acc[i][3];
        o1.x = acc[i][4]; o1.y = acc[i][5]; o1.z = acc[i][6]; o1.w = acc[i][7];
        if (BIAS) {
            const float4 b0 = *(const float4*)(bias + bn + tx * 4);
            const float4 b1 = *(const float4*)(bias + bn + 64 + tx * 4);
            o0.x += b0.x; o0.y += b0.y; o0.z += b0.z; o0.w += b0.w;
            o1.x += b1.x; o1.y += b1.y; o1.z += b1.z; o1.w += b1.w;
        }
        *(float4*)(C + (size_t)row * N + bn + tx * 4)      = o0;
        *(float4*)(C + (size_t)row * N + bn + 64 + tx * 4) = o1;
    }
}

// ---------------- dpfp: [CROWS*8, 64] -> [CROWS*8, 128], L1-normalized ----------------
__global__ __launch_bounds__(256)
void dpfp_kernel(const float* __restrict__ X, float* __restrict__ Y)
{
    const int gid  = blockIdx.x * 256 + threadIdx.x;
    const int wid  = gid >> 6;                 // row id
    const int lane = threadIdx.x & 63;
    const float xv = X[(size_t)wid * 64 + lane];
    const float ap = fmaxf(xv, 0.f);
    const float an = fmaxf(-xv, 0.f);
    const float a_prev = __shfl(ap, (lane + 63) & 63);   // lane-1 (lane0 -> lane63)
    const float b_prev = __shfl(an, (lane + 63) & 63);
    const float y0 = ap * ((lane == 0) ? b_prev : a_prev);
    const float y1 = an * ((lane == 0) ? a_prev : b_prev);
    float s = y0 + y1;
    s += __shfl_xor(s, 1);
    s += __shfl_xor(s, 2);
    s += __shfl_xor(s, 4);
    s += __shfl_xor(s, 8);
    s += __shfl_xor(s, 16);
    s += __shfl_xor(s, 32);
    const float inv = 1.f / (s + 1e-6f);
    Y[(size_t)wid * 128 + lane]      = y0 * inv;
    Y[(size_t)wid * 128 + 64 + lane] = y1 * inv;
}

// ---------------- gate: beta = sigmoid(x @ Wg), [32768, 8], whole sequence ----------------
__global__ __launch_bounds__(256)
void gemm_g_kernel(const float* __restrict__ X, const float* __restrict__ Wg,
                   float* __restrict__ Bt)
{
    const int idx = blockIdx.x * 256 + threadIdx.x;   // 262144 total
    const int row = idx >> 3;
    const int c   = idx & 7;
    const float4* x4 = (const float4*)(X + (size_t)row * DMODEL);
    float acc = 0.f;
    for (int k4 = 0; k4 < 128; ++k4) {
        const float4 xv = x4[k4];
        acc = fmaf(xv.x, Wg[(k4 * 4 + 0) * 8 + c], acc);
        acc = fmaf(xv.y, Wg[(k4 * 4 + 1) * 8 + c], acc);
        acc = fmaf(xv.z, Wg[(k4 * 4 + 2) * 8 + c], acc);
        acc = fmaf(xv.w, Wg[(k4 * 4 + 3) * 8 + c], acc);
    }
    Bt[idx] = 1.f / (1.f + expf(-acc));
}

// ---------------- scan ----------------
__device__ __forceinline__ float rowsum16(float x)
{
    x += __int_as_float(__builtin_amdgcn_update_dpp(0, __float_as_int(x), 0x121, 0xF, 0xF, true)); // row_ror:1
    x += __int_as_float(__builtin_amdgcn_update_dpp(0, __float_as_int(x), 0x122, 0xF, 0xF, true)); // row_ror:2
    x += __int_as_float(__builtin_amdgcn_update_dpp(0, __float_as_int(x), 0x124, 0xF, 0xF, true)); // row_ror:4
    x += __int_as_float(__builtin_amdgcn_update_dpp(0, __float_as_int(x), 0x128, 0xF, 0xF, true)); // row_ror:8
    return x;
}

__device__ __forceinline__ void async16(const float* g, float* l)
{
    __builtin_amdgcn_global_load_lds((const __attribute__((address_space(1))) void*)g,
                                     (__attribute__((address_space(3))) void*)l, 16, 0, 0);
}
__device__ __forceinline__ void async4(const float* g, float* l)
{
    __builtin_amdgcn_global_load_lds((const __attribute__((address_space(1))) void*)g,
                                     (__attribute__((address_space(3))) void*)l, 4, 0, 0);
}

// Row-independent delta-rule chains, one CHUNK of steps. Block = (b,h, row-group of 16).
// 256 threads = 16 rows x 16 col-lanes; thread's 8 cols are STRIDED {c+16j} so every
// per-step LDS read hits 16 distinct banks (zero conflicts; 4-way broadcast across rows
// is free). K/Q/V/beta staged 32 steps at a time into double-buffered LDS via
// global_load_lds; ONE barrier per 32 steps. Register pipeline prefetches step s+2.
__global__ __launch_bounds__(256)
void scan_kernel(const float* __restrict__ Qp, const float* __restrict__ Kp,
                 const float* __restrict__ Vd, const float* __restrict__ Bt,
                 float* __restrict__ outs, float* __restrict__ Wst,
                 int s0, int first)
{
    const int blk = blockIdx.x;
    const int bh  = blk & 63;
    const int rg  = blk >> 6;
    const int b   = bh >> 3;
    const int h   = bh & 7;
    const int t   = threadIdx.x;
    const int c      = t & 15;     // col lane
    const int rloc   = t >> 4;     // row within group of 16
    const int wv  = t >> 6;        // wave id 0..3
    const int ln  = t & 63;        // lane within wave

    __shared__ __align__(16) float sk[2][SB][PHI];
    __shared__ __align__(16) float sq[2][SB][PHI];
    __shared__ __align__(16) float sv[2][SB][16];
    __shared__ __align__(16) float sb2[2][SB];

    const size_t bh128 = (size_t)(b * 8 + h) * 128;

    float w[8];
    float* wslot = Wst + (size_t)blk * 2048 + t * 8;
    if (first) {
#pragma unroll
        for (int j = 0; j < 8; ++j) w[j] = 0.f;
    } else {
        const float4 w0 = *(const float4*)(wslot);
        const float4 w1 = *(const float4*)(wslot + 4);
        w[0] = w0.x; w[1] = w0.y; w[2] = w0.z; w[3] = w0.w;
        w[4] = w1.x; w[5] = w1.y; w[6] = w1.z; w[7] = w1.w;
    }

    // -------- staging: one superblock (32 steps) of K,Q,V,beta into LDS buffer sbuf ----
    auto stage = [&](int sbuf, int sb) {
        const int sqb = sb * SB;                 // first chunk-local step of superblock
        if (wv < 2) {
            // K: 1024 float4, waves 0,1 x 8 iters
#pragma unroll
            for (int i = 0; i < 8; ++i) {
                const int L  = i * 128 + wv * 64 + ln;   // 0..1023
                const int sl = L >> 5, c4 = L & 31;
                async16(Kp + (size_t)(sqb + sl) * 8192 + bh128 + c4 * 4,
                        &sk[sbuf][0][0] + L * 4);
            }
            // V: 128 float4, waves 0,1 x 1 iter
            {
                const int L  = wv * 64 + ln;             // 0..127
                const int sl = L >> 2, c4 = L & 3;
                async16(Vd + (size_t)(sqb + sl) * 4096 + b * 512 + h * 64 + rg * 16 + c4 * 4,
                        &sv[sbuf][0][0] + L * 4);
            }
        } else {
            // Q: 1024 float4, waves 2,3 x 8 iters
#pragma unroll
            for (int i = 0; i < 8; ++i) {
                const int L  = i * 128 + (wv - 2) * 64 + ln;
                const int sl = L >> 5, c4 = L & 31;
                async16(Qp + (size_t)(sqb + sl) * 8192 + bh128 + c4 * 4,
                        &sq[sbuf][0][0] + L * 4);
            }
            // beta: 32 floats, wave 2 lanes 0..31
            if (wv == 2 && ln < SB) {
                async4(Bt + (size_t)(s0 + sqb + ln) * 64 + b * 8 + h,
                       &sb2[sbuf][0] + ln);
            }
        }
    };

    struct Frag { float k[8], q[8], v, b; };
    Frag r[4];

    auto preload = [&](Frag& f, int sbuf, int sl) {
#pragma unroll
        for (int j = 0; j < 8; ++j) {
            f.k[j] = sk[sbuf][sl][c + 16 * j];
            f.q[j] = sq[sbuf][sl][c + 16 * j];
        }
        f.v = sv[sbuf][sl][rloc];
        f.b = sb2[sbuf][sl];
    };

    auto step_compute = [&](const Frag& f, int sq_) {
        // a = w . k  (two chains of 4 then combine), reduce over 16 col-lanes
        float a0 = w[0] * f.k[0];
        float a1 = w[4] * f.k[4];
        a0 = fmaf(w[1], f.k[1], a0); a1 = fmaf(w[5], f.k[5], a1);
        a0 = fmaf(w[2], f.k[2], a0); a1 = fmaf(w[6], f.k[6], a1);
        a0 = fmaf(w[3], f.k[3], a0); a1 = fmaf(w[7], f.k[7], a1);
        float a = rowsum16(a0 + a1);
        const float d = f.b * (f.v - a);
#pragma unroll
        for (int j = 0; j < 8; ++j) w[j] = fmaf(d, f.k[j], w[j]);
        float o0 = w[0] * f.q[0];
        float o1 = w[4] * f.q[4];
        o0 = fmaf(w[1], f.q[1], o0); o1 = fmaf(w[5], f.q[5], o1);
        o0 = fmaf(w[2], f.q[2], o0); o1 = fmaf(w[6], f.q[6], o1);
        o0 = fmaf(w[3], f.q[3], o0); o1 = fmaf(w[7], f.q[7], o1);
        const float o = rowsum16(o0 + o1);
        if (c == 0)
            outs[(size_t)(sq_ * BATCH + b) * DMODEL + h * DK + rg * 16 + rloc] = o;
    };

    stage(0, 0);
    for (int sb = 0; sb < NSB; ++sb) {
        const int buf = sb & 1;
        __syncthreads();                         // drains staged loads for buf (vmcnt)
        if (sb + 1 < NSB) stage(buf ^ 1, sb + 1);
        preload(r[0], buf, 0);
        preload(r[1], buf, 1);
#pragma unroll 4
        for (int s = 0; s < SB; ++s) {
            const int sp = (s + 2 < SB) ? s + 2 : SB - 1;
            preload(r[(s + 2) & 3], buf, sp);    // 2-step-ahead register prefetch
            step_compute(r[s & 3], sb * SB + s);
        }
    }

    // persist state for next chunk
    float4 w0, w1;
    w0.x = w[0]; w0.y = w[1]; w0.z = w[2]; w0.w = w[3];
    w1.x = w[4]; w1.y = w[5]; w1.z = w[6]; w1.w = w[7];
    *(float4*)(wslot)     = w0;
    *(float4*)(wslot + 4) = w1;
}

extern "C" void kernel_launch(void* const* d_in, const int* in_sizes, int n_in,
                              void* d_out, int out_size, void* d_ws, size_t ws_size,
                              hipStream_t stream)
{
    const float* x  = (const float*)d_in[0];
    const float* Wq = (const float*)d_in[1];
    const float* Wk = (const float*)d_in[2];
    const float* Wv = (const float*)d_in[3];
    const float* Wg = (const float*)d_in[4];
    const float* Wo = (const float*)d_in[5];
    const float* bo = (const float*)d_in[6];
    float* out = (float*)d_out;

    // workspace (floats), chunked to ~104 MB total:
    //   Qp[CROWS*1024] Kp[CROWS*1024] Vd[CROWS*512] tmp[CROWS*512] Bt[32768*8] Wst[256*2048]
    float* ws  = (float*)d_ws;
    float* Qp  = ws;
    float* Kp  = Qp + (size_t)CROWS * 1024;
    float* Vd  = Kp + (size_t)CROWS * 1024;
    float* tmp = Vd + (size_t)CROWS * 512;
    float* Bt  = tmp + (size_t)CROWS * 512;
    float* Wst = Bt + (size_t)(SEQ * BATCH) * 8;
    (void)in_sizes; (void)n_in; (void)out_size; (void)ws_size;

    const dim3 gg(CROWS / 128, 4);   // (64, 4) = 256 workgroups
    const int NCH = SEQ / CHUNK;     // 4

    gemm_g_kernel<<<(SEQ * BATCH * 8) / 256, 256, 0, stream>>>(x, Wg, Bt);

    for (int c = 0; c < NCH; ++c) {
        const float* xc = x + (size_t)c * CROWS * DMODEL;
        sgemm_kernel<false><<<gg, 256, 0, stream>>>(xc, Wq, nullptr, tmp, CROWS, DMODEL, DMODEL);
        dpfp_kernel<<<(CROWS * 8) / 4, 256, 0, stream>>>(tmp, Qp);
        sgemm_kernel<false><<<gg, 256, 0, stream>>>(xc, Wk, nullptr, tmp, CROWS, DMODEL, DMODEL);
        dpfp_kernel<<<(CROWS * 8) / 4, 256, 0, stream>>>(tmp, Kp);
        sgemm_kernel<false><<<gg, 256, 0, stream>>>(xc, Wv, nullptr, Vd, CROWS, DMODEL, DMODEL);
        scan_kernel<<<256, 256, 0, stream>>>(Qp, Kp, Vd, Bt, tmp, Wst,
                                             c * CHUNK, c == 0 ? 1 : 0);
        sgemm_kernel<true><<<gg, 256, 0, stream>>>(tmp, Wo, bo,
                                                   out + (size_t)c * CROWS * DMODEL,
                                                   CROWS, DMODEL, DMODEL);
    }
}

// Round 4
// 2016.654 us; speedup vs baseline: 1.8254x; 1.0434x over previous
//
#include <hip/hip_runtime.h>

#define SEQ 4096
#define BATCH 8
#define HEADS 8
#define DMODEL 512
#define DK 64
#define PHI 128
#define CHUNK 1024
#define CROWS (CHUNK * BATCH)          // 8192 rows per chunk
#define SB 32                          // scan superblock (steps staged per barrier)
#define NSB (CHUNK / SB)               // 32

// ---------------- fp32 SGEMM: C[M,N] = A[M,K] @ B[K,N] (+bias) ----------------
// 128x128 tile, BK=16, 256 threads, 8x8 micro-tile.
template <bool BIAS>
__global__ __launch_bounds__(256)
void sgemm_kernel(const float* __restrict__ A, const float* __restrict__ B,
                  const float* __restrict__ bias, float* __restrict__ C,
                  int M, int N, int K)
{
    __shared__ __align__(16) float As[16][132];   // transposed A tile: As[k][m]
    __shared__ __align__(16) float Bs[16][128];   // Bs[k][n]
    const int t  = threadIdx.x;
    const int tx = t & 15;
    const int ty = t >> 4;
    const int bm = blockIdx.x * 128;
    const int bn = blockIdx.y * 128;

    float acc[8][8];
#pragma unroll
    for (int i = 0; i < 8; ++i)
#pragma unroll
        for (int j = 0; j < 8; ++j) acc[i][j] = 0.f;

    for (int k0 = 0; k0 < K; k0 += 16) {
#pragma unroll
        for (int i = 0; i < 2; ++i) {           // A tile: 128 rows x 16 k
            int lin = t + i * 256;
            int m   = lin >> 2;
            int kq  = (lin & 3) << 2;
            const float4 av = *(const float4*)(A + (size_t)(bm + m) * K + k0 + kq);
            As[kq + 0][m] = av.x; As[kq + 1][m] = av.y;
            As[kq + 2][m] = av.z; As[kq + 3][m] = av.w;
        }
#pragma unroll
        for (int i = 0; i < 2; ++i) {           // B tile: 16 k x 128 n
            int lin = t + i * 256;
            int kk  = lin >> 5;
            int n4  = (lin & 31) << 2;
            *(float4*)(&Bs[kk][n4]) = *(const float4*)(B + (size_t)(k0 + kk) * N + bn + n4);
        }
        __syncthreads();
#pragma unroll
        for (int k = 0; k < 16; ++k) {
            float af[8], bf[8];
            *(float4*)&af[0] = *(const float4*)&As[k][ty * 8];
            *(float4*)&af[4] = *(const float4*)&As[k][ty * 8 + 4];
            *(float4*)&bf[0] = *(const float4*)&Bs[k][tx * 4];
            *(float4*)&bf[4] = *(const float4*)&Bs[k][64 + tx * 4];
#pragma unroll
            for (int i = 0; i < 8; ++i)
#pragma unroll
                for (int j = 0; j < 8; ++j) acc[i][j] = fmaf(af[i], bf[j], acc[i][j]);
        }
        __syncthreads();
    }

#pragma unroll
    for (int i = 0; i < 8; ++i) {
        const int row = bm + ty * 8 + i;
        float4 o0, o1;
        o0.x = acc[i][0]; o0.y = acc[i][1]; o0.z = acc[i][2]; o0.w = acc[i][3];
        o1.x = acc[i][4]; o1.y = acc[i][5]; o1.z = acc[i][6]; o1.w = acc[i][7];
        if (BIAS) {
            const float4 b0 = *(const float4*)(bias + bn + tx * 4);
            const float4 b1 = *(const float4*)(bias + bn + 64 + tx * 4);
            o0.x += b0.x; o0.y += b0.y; o0.z += b0.z; o0.w += b0.w;
            o1.x += b1.x; o1.y += b1.y; o1.z += b1.z; o1.w += b1.w;
        }
        *(float4*)(C + (size_t)row * N + bn + tx * 4)      = o0;
        *(float4*)(C + (size_t)row * N + bn + 64 + tx * 4) = o1;
    }
}

// ---------------- dpfp: [CROWS*8, 64] -> [CROWS*8, 128], L1-normalized ----------------
__global__ __launch_bounds__(256)
void dpfp_kernel(const float* __restrict__ X, float* __restrict__ Y)
{
    const int gid  = blockIdx.x * 256 + threadIdx.x;
    const int wid  = gid >> 6;                 // row id
    const int lane = threadIdx.x & 63;
    const float xv = X[(size_t)wid * 64 + lane];
    const float ap = fmaxf(xv, 0.f);
    const float an = fmaxf(-xv, 0.f);
    const float a_prev = __shfl(ap, (lane + 63) & 63);   // lane-1 (lane0 -> lane63)
    const float b_prev = __shfl(an, (lane + 63) & 63);
    const float y0 = ap * ((lane == 0) ? b_prev : a_prev);
    const float y1 = an * ((lane == 0) ? a_prev : b_prev);
    float s = y0 + y1;
    s += __shfl_xor(s, 1);
    s += __shfl_xor(s, 2);
    s += __shfl_xor(s, 4);
    s += __shfl_xor(s, 8);
    s += __shfl_xor(s, 16);
    s += __shfl_xor(s, 32);
    const float inv = 1.f / (s + 1e-6f);
    Y[(size_t)wid * 128 + lane]      = y0 * inv;
    Y[(size_t)wid * 128 + 64 + lane] = y1 * inv;
}

// ---------------- gate: beta = sigmoid(x @ Wg), [32768, 8], whole sequence ----------------
__global__ __launch_bounds__(256)
void gemm_g_kernel(const float* __restrict__ X, const float* __restrict__ Wg,
                   float* __restrict__ Bt)
{
    const int idx = blockIdx.x * 256 + threadIdx.x;   // 262144 total
    const int row = idx >> 3;
    const int c   = idx & 7;
    const float4* x4 = (const float4*)(X + (size_t)row * DMODEL);
    float acc = 0.f;
    for (int k4 = 0; k4 < 128; ++k4) {
        const float4 xv = x4[k4];
        acc = fmaf(xv.x, Wg[(k4 * 4 + 0) * 8 + c], acc);
        acc = fmaf(xv.y, Wg[(k4 * 4 + 1) * 8 + c], acc);
        acc = fmaf(xv.z, Wg[(k4 * 4 + 2) * 8 + c], acc);
        acc = fmaf(xv.w, Wg[(k4 * 4 + 3) * 8 + c], acc);
    }
    Bt[idx] = 1.f / (1.f + expf(-acc));
}

// ---------------- scan ----------------
__device__ __forceinline__ float rowsum16(float x)
{
    x += __int_as_float(__builtin_amdgcn_update_dpp(0, __float_as_int(x), 0x121, 0xF, 0xF, true)); // row_ror:1
    x += __int_as_float(__builtin_amdgcn_update_dpp(0, __float_as_int(x), 0x122, 0xF, 0xF, true)); // row_ror:2
    x += __int_as_float(__builtin_amdgcn_update_dpp(0, __float_as_int(x), 0x124, 0xF, 0xF, true)); // row_ror:4
    x += __int_as_float(__builtin_amdgcn_update_dpp(0, __float_as_int(x), 0x128, 0xF, 0xF, true)); // row_ror:8
    return x;
}

__device__ __forceinline__ void async16(const float* g, float* l)
{
    __builtin_amdgcn_global_load_lds((const __attribute__((address_space(1))) void*)g,
                                     (__attribute__((address_space(3))) void*)l, 16, 0, 0);
}
__device__ __forceinline__ void async4(const float* g, float* l)
{
    __builtin_amdgcn_global_load_lds((const __attribute__((address_space(1))) void*)g,
                                     (__attribute__((address_space(3))) void*)l, 4, 0, 0);
}

// Row-independent delta-rule chains, one CHUNK of steps. Block = (b,h, row-group of 16).
// 256 threads = 16 rows x 16 col-lanes. Thread c owns cols [4c,4c+4) U [64+4c,64+4c+4):
// per-step LDS reads are 4x ds_read_b128 (each 64 distinct dwords/16 lanes = 2/bank = free,
// 4-row broadcast free) + 2x b32 -- 3x fewer DS instrs than the stride-16 layout.
// K/Q/V/beta staged 32 steps at a time into double-buffered LDS via global_load_lds;
// ONE barrier per 32 steps. Full unroll -> all LDS addrs are base + 16-bit immediate.
__global__ __launch_bounds__(256)
void scan_kernel(const float* __restrict__ Qp, const float* __restrict__ Kp,
                 const float* __restrict__ Vd, const float* __restrict__ Bt,
                 float* __restrict__ outs, float* __restrict__ Wst,
                 int s0, int first)
{
    const int blk = blockIdx.x;
    const int bh  = blk & 63;
    const int rg  = blk >> 6;
    const int b   = bh >> 3;
    const int h   = bh & 7;
    const int t   = threadIdx.x;
    const int c      = t & 15;     // col lane
    const int rloc   = t >> 4;     // row within group of 16
    const int wv  = t >> 6;        // wave id 0..3
    const int ln  = t & 63;        // lane within wave

    __shared__ __align__(16) float sk[2][SB][PHI];
    __shared__ __align__(16) float sq[2][SB][PHI];
    __shared__ __align__(16) float sv[2][SB][16];
    __shared__ __align__(16) float sb2[2][SB];

    const size_t bh128 = (size_t)(b * 8 + h) * 128;

    // w[0..3] = cols [4c,4c+4), w[4..7] = cols [64+4c,64+4c+4)
    float w[8];
    float* wslot = Wst + (size_t)blk * 2048 + t * 8;
    if (first) {
#pragma unroll
        for (int j = 0; j < 8; ++j) w[j] = 0.f;
    } else {
        const float4 w0 = *(const float4*)(wslot);
        const float4 w1 = *(const float4*)(wslot + 4);
        w[0] = w0.x; w[1] = w0.y; w[2] = w0.z; w[3] = w0.w;
        w[4] = w1.x; w[5] = w1.y; w[6] = w1.z; w[7] = w1.w;
    }

    // -------- staging: one superblock (32 steps) of K,Q,V,beta into LDS buffer sbuf ----
    auto stage = [&](int sbuf, int sb) {
        const int sqb = sb * SB;                 // first chunk-local step of superblock
        if (wv < 2) {
            // K: 1024 float4, waves 0,1 x 8 iters
#pragma unroll
            for (int i = 0; i < 8; ++i) {
                const int L  = i * 128 + wv * 64 + ln;   // 0..1023
                const int sl = L >> 5, c4 = L & 31;
                async16(Kp + (size_t)(sqb + sl) * 8192 + bh128 + c4 * 4,
                        &sk[sbuf][0][0] + L * 4);
            }
            // V: 128 float4, waves 0,1 x 1 iter
            {
                const int L  = wv * 64 + ln;             // 0..127
                const int sl = L >> 2, c4 = L & 3;
                async16(Vd + (size_t)(sqb + sl) * 4096 + b * 512 + h * 64 + rg * 16 + c4 * 4,
                        &sv[sbuf][0][0] + L * 4);
            }
        } else {
            // Q: 1024 float4, waves 2,3 x 8 iters
#pragma unroll
            for (int i = 0; i < 8; ++i) {
                const int L  = i * 128 + (wv - 2) * 64 + ln;
                const int sl = L >> 5, c4 = L & 31;
                async16(Qp + (size_t)(sqb + sl) * 8192 + bh128 + c4 * 4,
                        &sq[sbuf][0][0] + L * 4);
            }
            // beta: 32 floats, wave 2 lanes 0..31
            if (wv == 2 && ln < SB) {
                async4(Bt + (size_t)(s0 + sqb + ln) * 64 + b * 8 + h,
                       &sb2[sbuf][0] + ln);
            }
        }
    };

    struct Frag { float4 k0, k1, q0, q1; float v, b; };
    Frag r[4];

    auto preload = [&](Frag& f, int sbuf, int sl) {
        f.k0 = *(const float4*)&sk[sbuf][sl][4 * c];
        f.k1 = *(const float4*)&sk[sbuf][sl][64 + 4 * c];
        f.q0 = *(const float4*)&sq[sbuf][sl][4 * c];
        f.q1 = *(const float4*)&sq[sbuf][sl][64 + 4 * c];
        f.v  = sv[sbuf][sl][rloc];
        f.b  = sb2[sbuf][sl];
    };

    auto step_compute = [&](const Frag& f, int sq_) {
        // a = w . k  (two parallel chains of 4), reduce over 16 col-lanes
        float a0 = w[0] * f.k0.x;
        float a1 = w[4] * f.k1.x;
        a0 = fmaf(w[1], f.k0.y, a0); a1 = fmaf(w[5], f.k1.y, a1);
        a0 = fmaf(w[2], f.k0.z, a0); a1 = fmaf(w[6], f.k1.z, a1);
        a0 = fmaf(w[3], f.k0.w, a0); a1 = fmaf(w[7], f.k1.w, a1);
        const float a = rowsum16(a0 + a1);
        const float d = f.b * (f.v - a);
        w[0] = fmaf(d, f.k0.x, w[0]);
        w[1] = fmaf(d, f.k0.y, w[1]);
        w[2] = fmaf(d, f.k0.z, w[2]);
        w[3] = fmaf(d, f.k0.w, w[3]);
        w[4] = fmaf(d, f.k1.x, w[4]);
        w[5] = fmaf(d, f.k1.y, w[5]);
        w[6] = fmaf(d, f.k1.z, w[6]);
        w[7] = fmaf(d, f.k1.w, w[7]);
        float o0 = w[0] * f.q0.x;
        float o1 = w[4] * f.q1.x;
        o0 = fmaf(w[1], f.q0.y, o0); o1 = fmaf(w[5], f.q1.y, o1);
        o0 = fmaf(w[2], f.q0.z, o0); o1 = fmaf(w[6], f.q1.z, o1);
        o0 = fmaf(w[3], f.q0.w, o0); o1 = fmaf(w[7], f.q1.w, o1);
        const float o = rowsum16(o0 + o1);
        if (c == 0)
            outs[(size_t)(sq_ * BATCH + b) * DMODEL + h * DK + rg * 16 + rloc] = o;
    };

    stage(0, 0);
    for (int sb = 0; sb < NSB; ++sb) {
        const int buf = sb & 1;
        __syncthreads();                         // drains staged loads for buf (vmcnt)
        if (sb + 1 < NSB) stage(buf ^ 1, sb + 1);
        preload(r[0], buf, 0);
        preload(r[1], buf, 1);
#pragma unroll
        for (int s = 0; s < SB; ++s) {
            const int sp = (s + 2 < SB) ? s + 2 : SB - 1;
            preload(r[(s + 2) & 3], buf, sp);    // 2-step-ahead register prefetch
            step_compute(r[s & 3], sb * SB + s);
        }
    }

    // persist state for next chunk
    float4 w0, w1;
    w0.x = w[0]; w0.y = w[1]; w0.z = w[2]; w0.w = w[3];
    w1.x = w[4]; w1.y = w[5]; w1.z = w[6]; w1.w = w[7];
    *(float4*)(wslot)     = w0;
    *(float4*)(wslot + 4) = w1;
}

extern "C" void kernel_launch(void* const* d_in, const int* in_sizes, int n_in,
                              void* d_out, int out_size, void* d_ws, size_t ws_size,
                              hipStream_t stream)
{
    const float* x  = (const float*)d_in[0];
    const float* Wq = (const float*)d_in[1];
    const float* Wk = (const float*)d_in[2];
    const float* Wv = (const float*)d_in[3];
    const float* Wg = (const float*)d_in[4];
    const float* Wo = (const float*)d_in[5];
    const float* bo = (const float*)d_in[6];
    float* out = (float*)d_out;

    // workspace (floats), chunked to ~104 MB total:
    //   Qp[CROWS*1024] Kp[CROWS*1024] Vd[CROWS*512] tmp[CROWS*512] Bt[32768*8] Wst[256*2048]
    float* ws  = (float*)d_ws;
    float* Qp  = ws;
    float* Kp  = Qp + (size_t)CROWS * 1024;
    float* Vd  = Kp + (size_t)CROWS * 1024;
    float* tmp = Vd + (size_t)CROWS * 512;
    float* Bt  = tmp + (size_t)CROWS * 512;
    float* Wst = Bt + (size_t)(SEQ * BATCH) * 8;
    (void)in_sizes; (void)n_in; (void)out_size; (void)ws_size;

    const dim3 gg(CROWS / 128, 4);   // (64, 4) = 256 workgroups
    const int NCH = SEQ / CHUNK;     // 4

    gemm_g_kernel<<<(SEQ * BATCH * 8) / 256, 256, 0, stream>>>(x, Wg, Bt);

    for (int c = 0; c < NCH; ++c) {
        const float* xc = x + (size_t)c * CROWS * DMODEL;
        sgemm_kernel<false><<<gg, 256, 0, stream>>>(xc, Wq, nullptr, tmp, CROWS, DMODEL, DMODEL);
        dpfp_kernel<<<(CROWS * 8) / 4, 256, 0, stream>>>(tmp, Qp);
        sgemm_kernel<false><<<gg, 256, 0, stream>>>(xc, Wk, nullptr, tmp, CROWS, DMODEL, DMODEL);
        dpfp_kernel<<<(CROWS * 8) / 4, 256, 0, stream>>>(tmp, Kp);
        sgemm_kernel<false><<<gg, 256, 0, stream>>>(xc, Wv, nullptr, Vd, CROWS, DMODEL, DMODEL);
        scan_kernel<<<256, 256, 0, stream>>>(Qp, Kp, Vd, Bt, tmp, Wst,
                                             c * CHUNK, c == 0 ? 1 : 0);
        sgemm_kernel<true><<<gg, 256, 0, stream>>>(tmp, Wo, bo,
                                                   out + (size_t)c * CROWS * DMODEL,
                                                   CROWS, DMODEL, DMODEL);
    }
}